// Round 13
// baseline (74.004 us; speedup 1.0000x reference)
//
#include <hip/hip_runtime.h>
#include <hip/hip_bf16.h>

typedef unsigned short ushort_t;
typedef unsigned int   uint_t;
typedef unsigned short ushortx8 __attribute__((ext_vector_type(8)));
typedef unsigned short ushortx4 __attribute__((ext_vector_type(4)));
typedef unsigned int   uintx4   __attribute__((ext_vector_type(4)));
typedef __bf16        bf16x8   __attribute__((ext_vector_type(8)));
typedef float         f32x4    __attribute__((ext_vector_type(4)));
typedef float         f32x16   __attribute__((ext_vector_type(16)));

#define SCALE_QL (0.29730177875068026f * 1.4426950408889634f) /* 128^-.25 * log2e */
#define OUT_HALF 2097152               /* B*C*H*W elements */
#define NSPLIT   8
#define KT_SPLIT 8                     /* 64-key tiles per split (512 keys) */
#define MFIX     32.0f                 /* fixed softmax shift (log2 domain) */

static __device__ __forceinline__ float fexp2(float x) {
    float r; asm("v_exp_f32 %0, %1" : "=v"(r) : "v"(x)); return r;
}
static __device__ __forceinline__ unsigned cvtpk_bf16(float lo, float hi) {
    unsigned r;
    asm("v_cvt_pk_bf16_f32 %0, %1, %2" : "=v"(r) : "v"(lo), "v"(hi));
    return r;
}
static __device__ __forceinline__ void pswap(unsigned& a, unsigned& b) {
    asm("v_permlane32_swap_b32 %0, %1" : "+v"(a), "+v"(b));
}
static __device__ __forceinline__ ushort_t bf16u(float f) {
    __hip_bfloat16 h = __float2bfloat16(f);
    return __builtin_bit_cast(ushort_t, h);
}
static __device__ __forceinline__ float bflo(unsigned u) {
    return __builtin_bit_cast(float, u << 16);
}
static __device__ __forceinline__ float bfhi(unsigned u) {
    return __builtin_bit_cast(float, u & 0xffff0000u);
}
static __device__ __forceinline__ void glds16(const void* g, void* l) {
    __builtin_amdgcn_global_load_lds(
        (const __attribute__((address_space(1))) unsigned int*)g,
        (__attribute__((address_space(3))) unsigned int*)l, 16, 0, 0);
}

// ---------------------------------------------------------------------------
// prep: pe [n][d][h] -> pet [h][n][d] f32;  wq/wk/wv f32 -> wb bf16 with
// row-local 16B-chunk xor swizzle (chunk ^= o&15) baked in.
__global__ __launch_bounds__(256) void prep_kernel(
    const float* __restrict__ pe,
    const float* __restrict__ wq, const float* __restrict__ wk,
    const float* __restrict__ wv,
    float* __restrict__ pet, ushort_t* __restrict__ wb)
{
    const int bid = blockIdx.x, t = threadIdx.x;
    if (bid < 1024) {
        int idx = bid * 256 + t;
        float2 p2 = *(const float2*)(pe + (size_t)idx * 2);
        pet[idx]                     = p2.x;
        pet[(size_t)4096 * 64 + idx] = p2.y;
        return;
    }
    const int b2 = bid - 1024;                 // 0..23
    const int p  = b2 >> 3;
    const float* w = (p == 0) ? wq : (p == 1) ? wk : wv;
    const int cid = (b2 & 7) * 256 + t;        // 16B-chunk id 0..2047
    const int o = cid >> 4, chunk = cid & 15;
    float4 f0 = *(const float4*)(w + o * 128 + chunk * 8);
    float4 f1 = *(const float4*)(w + o * 128 + chunk * 8 + 4);
    ushortx8 u;
    u[0] = bf16u(f0.x); u[1] = bf16u(f0.y); u[2] = bf16u(f0.z); u[3] = bf16u(f0.w);
    u[4] = bf16u(f1.x); u[5] = bf16u(f1.y); u[6] = bf16u(f1.z); u[7] = bf16u(f1.w);
    *(ushortx8*)(wb + p * 16384 + o * 128 + ((chunk ^ (o & 15)) << 3)) = u;
}

// ---------------------------------------------------------------------------
// Fused transpose + MFMA projection: per block 128 outputs x 64 tokens,
// K=128, ONE projection per block (p = blockIdx.z -> 768 blocks, 3/CU).
// grid (64 ntile, 4 b, 3 p), 256 thr (4 waves, each 32 output rows).
__global__ __launch_bounds__(256, 2) void proj_kernel(
    const float* __restrict__ x, const ushort_t* __restrict__ wb,
    const float* __restrict__ bq, const float* __restrict__ bk,
    const float* __restrict__ bv, const float* __restrict__ pet,
    ushort_t* __restrict__ qw, ushort_t* __restrict__ kw,
    ushort_t* __restrict__ vw)
{
    const int ntl = blockIdx.x;        // 64-token tile
    const int b = blockIdx.y, p = blockIdx.z;
    __shared__ __align__(16) ushort_t xt[64 * 128];            // [n64][c128] swz
    __shared__ __align__(16) union {
        ushort_t xs[128][68];                                   // staging
        ushort_t wt[16384];                                     // [o128][c128] swz
    } smu;
    const int t = threadIdx.x, lane = t & 63;
    const int wv_ = __builtin_amdgcn_readfirstlane(t >> 6);
    const int l16 = lane & 15, lhi = lane >> 4;

    // phase 1: x f32 [c][n-tile] -> bf16 xs[c][n]
    {
        const int cg = t >> 4, n0 = (t & 15) * 4;
#pragma unroll
        for (int i = 0; i < 8; ++i) {
            int c = i * 16 + cg;
            float4 f = *(const float4*)(x + ((size_t)(b * 128 + c)) * 4096 + ntl * 64 + n0);
            ushortx4 u;
            u[0] = bf16u(f.x); u[1] = bf16u(f.y); u[2] = bf16u(f.z); u[3] = bf16u(f.w);
            *(ushortx4*)(&smu.xs[c][n0]) = u;
        }
    }
    __syncthreads();
    // phase 2: transpose into xt[n][c], chunk-swizzled per row
    {
        const int n = t >> 2;
#pragma unroll
        for (int j = 0; j < 4; ++j) {
            int chunk = (t & 3) * 4 + j;
            ushortx8 u;
#pragma unroll
            for (int e = 0; e < 8; ++e) u[e] = smu.xs[chunk * 8 + e][n];
            *(ushortx8*)(xt + n * 128 + ((chunk ^ (n & 15)) << 3)) = u;
        }
    }
    __syncthreads();                   // xs reads done; wt may be overwritten

    // stage W for this p
    {
        const ushort_t* wsrc = wb + p * 16384;
#pragma unroll
        for (int j = 0; j < 8; ++j) {
            int row = wv_ * 32 + j * 4;
            glds16(wsrc + row * 128 + lane * 8, smu.wt + row * 128);
        }
    }

    const float* bias = (p == 0) ? bq : (p == 1) ? bk : bv;
    f32x4 bias4[2];
    bias4[0] = *(const f32x4*)(bias + wv_ * 32 + lhi * 4);
    bias4[1] = *(const f32x4*)(bias + wv_ * 32 + 16 + lhi * 4);
    f32x4 acc[2][4];
#pragma unroll
    for (int mf = 0; mf < 2; ++mf)
#pragma unroll
        for (int nf = 0; nf < 4; ++nf) acc[mf][nf] = bias4[mf];

    __syncthreads();                   // wt staged (barrier drains glds)

    const int nbase = ntl * 64;
    const char* xbp = (const char*)xt;
    const char* wbp = (const char*)smu.wt;
#pragma unroll
    for (int ks = 0; ks < 4; ++ks) {
        bf16x8 af[2];
#pragma unroll
        for (int mf = 0; mf < 2; ++mf) {
            int row = wv_ * 32 + mf * 16 + l16;
            af[mf] = __builtin_bit_cast(bf16x8, *(const ushortx8*)(
                wbp + row * 256 + ((((ks * 4 + lhi) ^ l16) & 15) << 4)));
        }
#pragma unroll
        for (int nf = 0; nf < 4; ++nf) {
            int row = nf * 16 + l16;
            bf16x8 bfr = __builtin_bit_cast(bf16x8, *(const ushortx8*)(
                xbp + row * 256 + ((((ks * 4 + lhi) ^ l16) & 15) << 4)));
            acc[0][nf] = __builtin_amdgcn_mfma_f32_16x16x32_bf16(af[0], bfr, acc[0][nf], 0, 0, 0);
            acc[1][nf] = __builtin_amdgcn_mfma_f32_16x16x32_bf16(af[1], bfr, acc[1][nf], 0, 0, 0);
        }
    }

    if (p == 2) {                      // V -> d-major [bh][d][n]
#pragma unroll
        for (int mf = 0; mf < 2; ++mf) {
            int o = wv_ * 32 + mf * 16 + lhi * 4;
            int h = o >> 6, d = o & 63;
            ushort_t* vb = vw + (((size_t)(b * 2 + h) * 64 + d)) * 4096 + nbase + l16;
#pragma unroll
            for (int nf = 0; nf < 4; ++nf)
#pragma unroll
                for (int r = 0; r < 4; ++r)
                    vb[(size_t)r * 4096 + nf * 16] = bf16u(acc[mf][nf][r]);
        }
    } else if (p == 0) {               // Q: +pe, *scale, token-major
#pragma unroll
        for (int mf = 0; mf < 2; ++mf) {
            int o = wv_ * 32 + mf * 16 + lhi * 4;
            int h = o >> 6, d = o & 63;
#pragma unroll
            for (int nf = 0; nf < 4; ++nf) {
                int n = nbase + nf * 16 + l16;
                f32x4 pe4 = *(const f32x4*)(pet + ((size_t)h * 4096 + n) * 64 + d);
                f32x4 q4 = (acc[mf][nf] + pe4) * SCALE_QL;
                ushortx4 s;
                s[0] = bf16u(q4[0]); s[1] = bf16u(q4[1]);
                s[2] = bf16u(q4[2]); s[3] = bf16u(q4[3]);
                *(ushortx4*)(qw + ((size_t)(b * 2 + h) * 4096 + n) * 64 + d) = s;
            }
        }
    } else {                           // K: token-major
#pragma unroll
        for (int mf = 0; mf < 2; ++mf) {
            int o = wv_ * 32 + mf * 16 + lhi * 4;
            int h = o >> 6, d = o & 63;
#pragma unroll
            for (int nf = 0; nf < 4; ++nf) {
                int n = nbase + nf * 16 + l16;
                f32x4 k4 = acc[mf][nf];
                ushortx4 s;
                s[0] = bf16u(k4[0]); s[1] = bf16u(k4[1]);
                s[2] = bf16u(k4[2]); s[3] = bf16u(k4[3]);
                *(ushortx4*)(kw + ((size_t)(b * 2 + h) * 4096 + n) * 64 + d) = s;
            }
        }
    }
}

// ---------------------------------------------------------------------------
// Flash attention, 32x32 MFMA, swapped (S^T = K*Q), 32 q per wave,
// 8 waves (512 thr), FIXED-M softmax p = exp2(s - 32), deferred ls reduce.
// KVBLK=64, 32 KB LDS dbuf, VGPR ~52 (<=64 granule) -> with NSPLIT=8 the
// grid is 1024 blocks = 4 blocks/CU = 32 waves/CU (was 2 blocks -> 50% cap).
// grid (16 qtile(256q), 8 bh, NSPLIT).
__global__ __launch_bounds__(512, 4) void attn_kernel(
    const ushort_t* __restrict__ qw, const ushort_t* __restrict__ kw,
    const ushort_t* __restrict__ vw, uint_t* __restrict__ opart,
    float* __restrict__ lspart)
{
    const int qt = blockIdx.x, bh = blockIdx.y, sp = blockIdx.z;
    const int t = threadIdx.x, lane = t & 63;
    const int wv = t >> 6;                       // 0..7
    const int l31 = lane & 31, hi = lane >> 5;

    __shared__ __align__(16) ushort_t Kt[2 * 64 * 64];   // dbuf [key][d] swz
    __shared__ __align__(16) ushort_t Vt[2 * 64 * 64];   // dbuf [d][key] swz

    // Q B-frags [ks]: lane holds Q[q = qb+l31][d = ks*16+hi*8 ..+8]
    const int qb = qt * 256 + wv * 32;
    bf16x8 qf[4];
#pragma unroll
    for (int ks = 0; ks < 4; ++ks)
        qf[ks] = __builtin_bit_cast(bf16x8, *(const ushortx8*)(
            qw + ((size_t)bh * 4096 + qb + l31) * 64 + ks * 16 + hi * 8));

    const ushort_t* kgb = kw + ((size_t)bh * 4096) * 64;
    const ushort_t* vgb = vw + ((size_t)bh * 64) * 4096;

    // staging: wave covers rows [wv*8, wv*8+8); source pre-XOR-swizzled.
    const int srow = lane >> 3, c7 = lane & 7;
    const int rb = wv * 8;
    const int swz = (c7 ^ srow) << 3;
    const size_t koff = (size_t)(rb + srow) * 64 + swz;
    const size_t voff = (size_t)(rb + srow) * 4096 + swz;

    const f32x16 z16 = {0,0,0,0,0,0,0,0,0,0,0,0,0,0,0,0};
    f32x16 oa0 = z16, oa1 = z16;       // O^T[d 0..31 | 32..63][q=l31]
    float ls0 = 0.f;                   // per-lane half-sum

    const int kt0 = sp * KT_SPLIT;

#define STAGE(buf, ktb)                                                       \
    {                                                                         \
        glds16(kgb + (size_t)(ktb) * 4096 + koff,                             \
               Kt + (buf) * 4096 + (size_t)rb * 64);                          \
        glds16(vgb + (size_t)(ktb) * 64 + voff,                               \
               Vt + (buf) * 4096 + (size_t)rb * 64);                          \
    }

    STAGE(0, kt0)
    __syncthreads();

    const int sw7 = l31 & 7;
    int cur = 0;
    for (int it = 0; it < KT_SPLIT; ++it) {
        const int itn = (it + 1 < KT_SPLIT) ? it + 1 : it;
        STAGE(cur ^ 1, kt0 + itn)

        const char* kc = (const char*)(Kt + cur * 4096);
        const char* vc = (const char*)(Vt + cur * 4096);

#pragma unroll
        for (int c = 0; c < 2; ++c) {            // 32-key chain
            const int kbase = (c * 32 + l31) * 128;
            bf16x8 kf[4];
#pragma unroll
            for (int ks = 0; ks < 4; ++ks)
                kf[ks] = __builtin_bit_cast(bf16x8, *(const ushortx8*)(
                    kc + kbase + (((ks * 2 + hi) ^ sw7) << 4)));

            f32x16 s0 = z16;
            __builtin_amdgcn_s_setprio(1);
#pragma unroll
            for (int ks = 0; ks < 4; ++ks)
                s0 = __builtin_amdgcn_mfma_f32_32x32x16_bf16(kf[ks], qf[ks], s0, 0, 0, 0);
            __builtin_amdgcn_s_setprio(0);

            // ---- fixed-M softmax: branch-free, no cross-lane ops ----
            float p[16];
#pragma unroll
            for (int r = 0; r < 16; ++r) p[r] = fexp2(s0[r] - MFIX);
            float q0 = (p[0] + p[1]) + (p[2] + p[3]);
            float q1 = (p[4] + p[5]) + (p[6] + p[7]);
            float q2 = (p[8] + p[9]) + (p[10] + p[11]);
            float q3 = (p[12] + p[13]) + (p[14] + p[15]);
            ls0 += (q0 + q1) + (q2 + q3);
            unsigned c0 = cvtpk_bf16(p[0], p[1]);
            unsigned c1 = cvtpk_bf16(p[2], p[3]);
            unsigned c2 = cvtpk_bf16(p[4], p[5]);
            unsigned c3 = cvtpk_bf16(p[6], p[7]);
            unsigned c4 = cvtpk_bf16(p[8], p[9]);
            unsigned c5 = cvtpk_bf16(p[10], p[11]);
            unsigned c6 = cvtpk_bf16(p[12], p[13]);
            unsigned c7x = cvtpk_bf16(p[14], p[15]);
            pswap(c0, c2); pswap(c1, c3); pswap(c4, c6); pswap(c5, c7x);
            bf16x8 pfa, pfb;
            { uintx4 u; u[0] = c0; u[1] = c1; u[2] = c2; u[3] = c3;
              pfa = __builtin_bit_cast(bf16x8, u); }
            { uintx4 u; u[0] = c4; u[1] = c5; u[2] = c6; u[3] = c7x;
              pfb = __builtin_bit_cast(bf16x8, u); }

            // ---- O^T += V^T P^T ----
            __builtin_amdgcn_s_setprio(1);
            {
                const int vb0 = l31 * 128;
                bf16x8 vf0 = __builtin_bit_cast(bf16x8, *(const ushortx8*)(
                    vc + vb0 + ((((c * 2 + 0) * 2 + hi) ^ sw7) << 4)));
                bf16x8 vf1 = __builtin_bit_cast(bf16x8, *(const ushortx8*)(
                    vc + vb0 + ((((c * 2 + 1) * 2 + hi) ^ sw7) << 4)));
                oa0 = __builtin_amdgcn_mfma_f32_32x32x16_bf16(vf0, pfa, oa0, 0, 0, 0);
                oa0 = __builtin_amdgcn_mfma_f32_32x32x16_bf16(vf1, pfb, oa0, 0, 0, 0);
            }
            {
                const int vb1 = (32 + l31) * 128;
                bf16x8 vf0 = __builtin_bit_cast(bf16x8, *(const ushortx8*)(
                    vc + vb1 + ((((c * 2 + 0) * 2 + hi) ^ sw7) << 4)));
                bf16x8 vf1 = __builtin_bit_cast(bf16x8, *(const ushortx8*)(
                    vc + vb1 + ((((c * 2 + 1) * 2 + hi) ^ sw7) << 4)));
                oa1 = __builtin_amdgcn_mfma_f32_32x32x16_bf16(vf0, pfa, oa1, 0, 0, 0);
                oa1 = __builtin_amdgcn_mfma_f32_32x32x16_bf16(vf1, pfb, oa1, 0, 0, 0);
            }
            __builtin_amdgcn_s_setprio(0);
        }

        __syncthreads();                 // drains prefetch glds + orders dbuf
        cur ^= 1;
    }

    // epilogue: bf16-pack unnormalized O partials, coalesced dump
    const int pidx = (qt * 8 + bh) * NSPLIT + sp;
#define STORE_OA(OA, DT)                                                      \
    {                                                                         \
        uintx4 u0, u1;                                                        \
        u0[0] = cvtpk_bf16(OA[0], OA[1]);  u0[1] = cvtpk_bf16(OA[2], OA[3]);  \
        u0[2] = cvtpk_bf16(OA[4], OA[5]);  u0[3] = cvtpk_bf16(OA[6], OA[7]);  \
        u1[0] = cvtpk_bf16(OA[8], OA[9]);  u1[1] = cvtpk_bf16(OA[10], OA[11]);\
        u1[2] = cvtpk_bf16(OA[12], OA[13]);u1[3] = cvtpk_bf16(OA[14], OA[15]);\
        uint_t* dst = opart +                                                 \
            (((size_t)pidx * 8 + wv) * 2 + (DT)) * 512 + lane * 8;            \
        *(uintx4*)dst = u0; *(uintx4*)(dst + 4) = u1;                         \
    }
    STORE_OA(oa0, 0) STORE_OA(oa1, 1)

    ls0 += __shfl_xor(ls0, 32, 64);      // combine the two key halves once
    if (hi == 0)
        lspart[(pidx * 8 + wv) * 32 + l31] = ls0;
}

// ---------------------------------------------------------------------------
// Combine NSPLIT partials (den = sum of ls; fixed-M => no exp), normalize,
// write out twice. grid (16 qt, 8 bh), 512 thr mirroring attn lanes.
__global__ __launch_bounds__(512) void combine_kernel(
    const uint_t* __restrict__ opart, const float* __restrict__ lspart,
    float* __restrict__ out)
{
    const int qt = blockIdx.x, bh = blockIdx.y;
    const int b = bh >> 1, h = bh & 1;
    const int t = threadIdx.x, lane = t & 63, wa = t >> 6;
    const int l31 = lane & 31, hi = lane >> 5;
    const int pbase = (qt * 8 + bh) * NSPLIT;
    const int dtbl[8] = {0, 2, 8, 10, 16, 18, 24, 26};

    float den = 0.f;
#pragma unroll
    for (int sp = 0; sp < NSPLIT; ++sp)
        den += lspart[((pbase + sp) * 8 + wa) * 32 + l31];
    float inv = 1.f / den;

    const int q = qt * 256 + wa * 32 + l31;
#pragma unroll
    for (int dt = 0; dt < 2; ++dt) {
        float acc[16];
#pragma unroll
        for (int i = 0; i < 16; ++i) acc[i] = 0.f;
#pragma unroll
        for (int sp = 0; sp < NSPLIT; ++sp) {
            const uint_t* src = opart +
                (((size_t)(pbase + sp) * 8 + wa) * 2 + dt) * 512 + lane * 8;
            uintx4 a = *(const uintx4*)src;
            uintx4 b2 = *(const uintx4*)(src + 4);
#pragma unroll
            for (int j = 0; j < 4; ++j) {
                acc[2 * j]     += bflo(a[j]);
                acc[2 * j + 1] += bfhi(a[j]);
                acc[8 + 2 * j] += bflo(b2[j]);
                acc[9 + 2 * j] += bfhi(b2[j]);
            }
        }
#pragma unroll
        for (int j = 0; j < 8; ++j) {
            int d = dt * 32 + 4 * hi + dtbl[j];
            float v0 = acc[2 * j] * inv;
            float v1 = acc[2 * j + 1] * inv;
            size_t o0 = ((size_t)(b * 128 + d * 2 + h)) * 4096 + q;
            out[o0] = v0;
            out[o0 + OUT_HALF] = v0;
            size_t o1 = o0 + 2 * 4096;
            out[o1] = v1;
            out[o1 + OUT_HALF] = v1;
        }
    }
}

// ---------------------------------------------------------------------------
extern "C" void kernel_launch(void* const* d_in, const int* in_sizes, int n_in,
                              void* d_out, int out_size, void* d_ws, size_t ws_size,
                              hipStream_t stream) {
    const float* x  = (const float*)d_in[0];
    const float* wq = (const float*)d_in[1];
    const float* bq = (const float*)d_in[2];
    const float* wk = (const float*)d_in[3];
    const float* bk = (const float*)d_in[4];
    const float* wv = (const float*)d_in[5];
    const float* bv = (const float*)d_in[6];
    const float* pe = (const float*)d_in[7];
    float* out = (float*)d_out;

    // ws layout (47.6 MB total; lspart aliases dead pet, wb dies before opart):
    //   0- 2 MB  pet (proj)  /  lspart (attn, written after pet is dead)
    //   2-14 MB  qw, kw, vw
    //  14-47.6   opart (attn; wb at 31 MB is read by proj before attn runs)
    char* ws = (char*)d_ws;
    float*    pet   = (float*)ws;                                   // 2 MB
    float*    lsprt = (float*)ws;                                   // 1 MB (aliases pet)
    ushort_t* qw    = (ushort_t*)(ws + (size_t)2  * 1024 * 1024);   // 4 MB
    ushort_t* kw    = (ushort_t*)(ws + (size_t)6  * 1024 * 1024);   // 4 MB
    ushort_t* vw    = (ushort_t*)(ws + (size_t)10 * 1024 * 1024);   // 4 MB
    uint_t*   opart = (uint_t*)(ws + (size_t)14 * 1024 * 1024);     // 33.6 MB (attn)
    ushort_t* wb    = (ushort_t*)(ws + (size_t)31 * 1024 * 1024);   // 96 KB (proj, dies before attn)

    hipLaunchKernelGGL(prep_kernel, dim3(1048), dim3(256), 0, stream,
                       pe, wq, wk, wv, pet, wb);
    hipLaunchKernelGGL(proj_kernel, dim3(64, 4, 3), dim3(256), 0, stream,
                       x, wb, bq, bk, bv, pet, qw, kw, vw);
    hipLaunchKernelGGL(attn_kernel, dim3(16, 8, NSPLIT), dim3(512), 0, stream,
                       qw, kw, vw, opart, lsprt);
    hipLaunchKernelGGL(combine_kernel, dim3(16, 8), dim3(512), 0, stream,
                       opart, lsprt, out);
}

// Round 16
// 71.396 us; speedup vs baseline: 1.0365x; 1.0365x over previous
//
#include <hip/hip_runtime.h>
#include <hip/hip_bf16.h>

typedef unsigned short ushort_t;
typedef unsigned int   uint_t;
typedef unsigned short ushortx8 __attribute__((ext_vector_type(8)));
typedef unsigned short ushortx4 __attribute__((ext_vector_type(4)));
typedef unsigned int   uintx4   __attribute__((ext_vector_type(4)));
typedef __bf16        bf16x8   __attribute__((ext_vector_type(8)));
typedef float         f32x4    __attribute__((ext_vector_type(4)));
typedef float         f32x16   __attribute__((ext_vector_type(16)));

#define SCALE_QL (0.29730177875068026f * 1.4426950408889634f) /* 128^-.25 * log2e */
#define OUT_HALF 2097152               /* B*C*H*W elements */
#define NSPLIT   4
#define KT_SPLIT 16                    /* 64-key tiles per split (1024 keys) */
#define MFIX     32.0f                 /* fixed softmax shift (log2 domain) */

static __device__ __forceinline__ float fexp2(float x) {
    float r; asm("v_exp_f32 %0, %1" : "=v"(r) : "v"(x)); return r;
}
static __device__ __forceinline__ unsigned cvtpk_bf16(float lo, float hi) {
    unsigned r;
    asm("v_cvt_pk_bf16_f32 %0, %1, %2" : "=v"(r) : "v"(lo), "v"(hi));
    return r;
}
static __device__ __forceinline__ void pswap(unsigned& a, unsigned& b) {
    asm("v_permlane32_swap_b32 %0, %1" : "+v"(a), "+v"(b));
}
static __device__ __forceinline__ ushort_t bf16u(float f) {
    __hip_bfloat16 h = __float2bfloat16(f);
    return __builtin_bit_cast(ushort_t, h);
}
static __device__ __forceinline__ float bflo(unsigned u) {
    return __builtin_bit_cast(float, u << 16);
}
static __device__ __forceinline__ float bfhi(unsigned u) {
    return __builtin_bit_cast(float, u & 0xffff0000u);
}
static __device__ __forceinline__ void glds16(const void* g, void* l) {
    __builtin_amdgcn_global_load_lds(
        (const __attribute__((address_space(1))) unsigned int*)g,
        (__attribute__((address_space(3))) unsigned int*)l, 16, 0, 0);
}

// ---------------------------------------------------------------------------
// prep: pe [n][d][h] -> pet [h][n][d] f32;  wq/wk/wv f32 -> wb bf16 with
// row-local 16B-chunk xor swizzle (chunk ^= o&15) baked in.
__global__ __launch_bounds__(256) void prep_kernel(
    const float* __restrict__ pe,
    const float* __restrict__ wq, const float* __restrict__ wk,
    const float* __restrict__ wv,
    float* __restrict__ pet, ushort_t* __restrict__ wb)
{
    const int bid = blockIdx.x, t = threadIdx.x;
    if (bid < 1024) {
        int idx = bid * 256 + t;
        float2 p2 = *(const float2*)(pe + (size_t)idx * 2);
        pet[idx]                     = p2.x;
        pet[(size_t)4096 * 64 + idx] = p2.y;
        return;
    }
    const int b2 = bid - 1024;                 // 0..23
    const int p  = b2 >> 3;
    const float* w = (p == 0) ? wq : (p == 1) ? wk : wv;
    const int cid = (b2 & 7) * 256 + t;        // 16B-chunk id 0..2047
    const int o = cid >> 4, chunk = cid & 15;
    float4 f0 = *(const float4*)(w + o * 128 + chunk * 8);
    float4 f1 = *(const float4*)(w + o * 128 + chunk * 8 + 4);
    ushortx8 u;
    u[0] = bf16u(f0.x); u[1] = bf16u(f0.y); u[2] = bf16u(f0.z); u[3] = bf16u(f0.w);
    u[4] = bf16u(f1.x); u[5] = bf16u(f1.y); u[6] = bf16u(f1.z); u[7] = bf16u(f1.w);
    *(ushortx8*)(wb + p * 16384 + o * 128 + ((chunk ^ (o & 15)) << 3)) = u;
}

// ---------------------------------------------------------------------------
// Fused transpose + MFMA projection: per block 128 outputs x 64 tokens,
// K=128, ONE projection per block (p = blockIdx.z -> 768 blocks, 3/CU).
// grid (64 ntile, 4 b, 3 p), 256 thr (4 waves, each 32 output rows).
__global__ __launch_bounds__(256, 2) void proj_kernel(
    const float* __restrict__ x, const ushort_t* __restrict__ wb,
    const float* __restrict__ bq, const float* __restrict__ bk,
    const float* __restrict__ bv, const float* __restrict__ pet,
    ushort_t* __restrict__ qw, ushort_t* __restrict__ kw,
    ushort_t* __restrict__ vw)
{
    const int ntl = blockIdx.x;        // 64-token tile
    const int b = blockIdx.y, p = blockIdx.z;
    __shared__ __align__(16) ushort_t xt[64 * 128];            // [n64][c128] swz
    __shared__ __align__(16) union {
        ushort_t xs[128][68];                                   // staging
        ushort_t wt[16384];                                     // [o128][c128] swz
    } smu;
    const int t = threadIdx.x, lane = t & 63;
    const int wv_ = __builtin_amdgcn_readfirstlane(t >> 6);
    const int l16 = lane & 15, lhi = lane >> 4;

    // phase 1: x f32 [c][n-tile] -> bf16 xs[c][n]
    {
        const int cg = t >> 4, n0 = (t & 15) * 4;
#pragma unroll
        for (int i = 0; i < 8; ++i) {
            int c = i * 16 + cg;
            float4 f = *(const float4*)(x + ((size_t)(b * 128 + c)) * 4096 + ntl * 64 + n0);
            ushortx4 u;
            u[0] = bf16u(f.x); u[1] = bf16u(f.y); u[2] = bf16u(f.z); u[3] = bf16u(f.w);
            *(ushortx4*)(&smu.xs[c][n0]) = u;
        }
    }
    __syncthreads();
    // phase 2: transpose into xt[n][c], chunk-swizzled per row
    {
        const int n = t >> 2;
#pragma unroll
        for (int j = 0; j < 4; ++j) {
            int chunk = (t & 3) * 4 + j;
            ushortx8 u;
#pragma unroll
            for (int e = 0; e < 8; ++e) u[e] = smu.xs[chunk * 8 + e][n];
            *(ushortx8*)(xt + n * 128 + ((chunk ^ (n & 15)) << 3)) = u;
        }
    }
    __syncthreads();                   // xs reads done; wt may be overwritten

    // stage W for this p
    {
        const ushort_t* wsrc = wb + p * 16384;
#pragma unroll
        for (int j = 0; j < 8; ++j) {
            int row = wv_ * 32 + j * 4;
            glds16(wsrc + row * 128 + lane * 8, smu.wt + row * 128);
        }
    }

    const float* bias = (p == 0) ? bq : (p == 1) ? bk : bv;
    f32x4 bias4[2];
    bias4[0] = *(const f32x4*)(bias + wv_ * 32 + lhi * 4);
    bias4[1] = *(const f32x4*)(bias + wv_ * 32 + 16 + lhi * 4);
    f32x4 acc[2][4];
#pragma unroll
    for (int mf = 0; mf < 2; ++mf)
#pragma unroll
        for (int nf = 0; nf < 4; ++nf) acc[mf][nf] = bias4[mf];

    __syncthreads();                   // wt staged (barrier drains glds)

    const int nbase = ntl * 64;
    const char* xbp = (const char*)xt;
    const char* wbp = (const char*)smu.wt;
#pragma unroll
    for (int ks = 0; ks < 4; ++ks) {
        bf16x8 af[2];
#pragma unroll
        for (int mf = 0; mf < 2; ++mf) {
            int row = wv_ * 32 + mf * 16 + l16;
            af[mf] = __builtin_bit_cast(bf16x8, *(const ushortx8*)(
                wbp + row * 256 + ((((ks * 4 + lhi) ^ l16) & 15) << 4)));
        }
#pragma unroll
        for (int nf = 0; nf < 4; ++nf) {
            int row = nf * 16 + l16;
            bf16x8 bfr = __builtin_bit_cast(bf16x8, *(const ushortx8*)(
                xbp + row * 256 + ((((ks * 4 + lhi) ^ l16) & 15) << 4)));
            acc[0][nf] = __builtin_amdgcn_mfma_f32_16x16x32_bf16(af[0], bfr, acc[0][nf], 0, 0, 0);
            acc[1][nf] = __builtin_amdgcn_mfma_f32_16x16x32_bf16(af[1], bfr, acc[1][nf], 0, 0, 0);
        }
    }

    if (p == 2) {                      // V -> d-major [bh][d][n]
#pragma unroll
        for (int mf = 0; mf < 2; ++mf) {
            int o = wv_ * 32 + mf * 16 + lhi * 4;
            int h = o >> 6, d = o & 63;
            ushort_t* vb = vw + (((size_t)(b * 2 + h) * 64 + d)) * 4096 + nbase + l16;
#pragma unroll
            for (int nf = 0; nf < 4; ++nf)
#pragma unroll
                for (int r = 0; r < 4; ++r)
                    vb[(size_t)r * 4096 + nf * 16] = bf16u(acc[mf][nf][r]);
        }
    } else if (p == 0) {               // Q: +pe, *scale, token-major
#pragma unroll
        for (int mf = 0; mf < 2; ++mf) {
            int o = wv_ * 32 + mf * 16 + lhi * 4;
            int h = o >> 6, d = o & 63;
#pragma unroll
            for (int nf = 0; nf < 4; ++nf) {
                int n = nbase + nf * 16 + l16;
                f32x4 pe4 = *(const f32x4*)(pet + ((size_t)h * 4096 + n) * 64 + d);
                f32x4 q4 = (acc[mf][nf] + pe4) * SCALE_QL;
                ushortx4 s;
                s[0] = bf16u(q4[0]); s[1] = bf16u(q4[1]);
                s[2] = bf16u(q4[2]); s[3] = bf16u(q4[3]);
                *(ushortx4*)(qw + ((size_t)(b * 2 + h) * 4096 + n) * 64 + d) = s;
            }
        }
    } else {                           // K: token-major
#pragma unroll
        for (int mf = 0; mf < 2; ++mf) {
            int o = wv_ * 32 + mf * 16 + lhi * 4;
            int h = o >> 6, d = o & 63;
#pragma unroll
            for (int nf = 0; nf < 4; ++nf) {
                int n = nbase + nf * 16 + l16;
                f32x4 k4 = acc[mf][nf];
                ushortx4 s;
                s[0] = bf16u(k4[0]); s[1] = bf16u(k4[1]);
                s[2] = bf16u(k4[2]); s[3] = bf16u(k4[3]);
                *(ushortx4*)(kw + ((size_t)(b * 2 + h) * 4096 + n) * 64 + d) = s;
            }
        }
    }
}

// ---------------------------------------------------------------------------
// Flash attention, 32x32 MFMA, swapped (S^T = K*Q), 32 q per wave,
// 8 waves (512 thr), FIXED-M softmax p = exp2(s - 32) (explicit subtract —
// folding -32 into the MFMA C-in miscompiled in R14/R15, do NOT re-try),
// deferred ls reduce. XCD-aware block remap: the 16 qt-blocks sharing one
// (bh,sp) K/V split (256 KB) land on ONE XCD's L2.
// K,V double-buffered LDS (32 KB), glds16 prefetch, 1 barrier/iter.
// grid (16 qtile(256q), 8 bh, NSPLIT).
__global__ __launch_bounds__(512, 4) void attn_kernel(
    const ushort_t* __restrict__ qw, const ushort_t* __restrict__ kw,
    const ushort_t* __restrict__ vw, uint_t* __restrict__ opart,
    float* __restrict__ lspart)
{
    // bijective XCD remap: raw -> swb=(raw&7)*64+(raw>>3); all 16 blocks of a
    // (bh,sp) group then have raw%8 == const -> same XCD (512 = 8*64).
    const int raw = blockIdx.x + 16 * (blockIdx.y + 8 * blockIdx.z);
    const int swb = (raw & 7) * 64 + (raw >> 3);
    const int qt = swb & 15, bh = (swb >> 4) & 7, sp = swb >> 7;
    const int t = threadIdx.x, lane = t & 63;
    const int wv = t >> 6;                       // 0..7
    const int l31 = lane & 31, hi = lane >> 5;

    __shared__ __align__(16) ushort_t Kt[2 * 64 * 64];   // dbuf [key][d] swz
    __shared__ __align__(16) ushort_t Vt[2 * 64 * 64];   // dbuf [d][key] swz

    // Q B-frags [ks]: lane holds Q[q = qb+l31][d = ks*16+hi*8 ..+8]
    const int qb = qt * 256 + wv * 32;
    bf16x8 qf[4];
#pragma unroll
    for (int ks = 0; ks < 4; ++ks)
        qf[ks] = __builtin_bit_cast(bf16x8, *(const ushortx8*)(
            qw + ((size_t)bh * 4096 + qb + l31) * 64 + ks * 16 + hi * 8));

    const ushort_t* kgb = kw + ((size_t)bh * 4096) * 64;
    const ushort_t* vgb = vw + ((size_t)bh * 64) * 4096;

    // staging: wave covers rows [wv*8, wv*8+8); source pre-XOR-swizzled.
    const int srow = lane >> 3, c7 = lane & 7;
    const int rb = wv * 8;
    const int swz = (c7 ^ srow) << 3;
    const size_t koff = (size_t)(rb + srow) * 64 + swz;
    const size_t voff = (size_t)(rb + srow) * 4096 + swz;

    const f32x16 z16 = {0,0,0,0,0,0,0,0,0,0,0,0,0,0,0,0};
    f32x16 oa0 = z16, oa1 = z16;       // O^T[d 0..31 | 32..63][q=l31]
    float ls0 = 0.f;                   // per-lane half-sum

    const int kt0 = sp * KT_SPLIT;

#define STAGE(buf, ktb)                                                       \
    {                                                                         \
        glds16(kgb + (size_t)(ktb) * 4096 + koff,                             \
               Kt + (buf) * 4096 + (size_t)rb * 64);                          \
        glds16(vgb + (size_t)(ktb) * 64 + voff,                               \
               Vt + (buf) * 4096 + (size_t)rb * 64);                          \
    }

    STAGE(0, kt0)
    __syncthreads();

    const int sw7 = l31 & 7;
    int cur = 0;
    for (int it = 0; it < KT_SPLIT; ++it) {
        const int itn = (it + 1 < KT_SPLIT) ? it + 1 : it;
        STAGE(cur ^ 1, kt0 + itn)

        const char* kc = (const char*)(Kt + cur * 4096);
        const char* vc = (const char*)(Vt + cur * 4096);

#pragma unroll
        for (int c = 0; c < 2; ++c) {            // 32-key chain
            const int kbase = (c * 32 + l31) * 128;
            bf16x8 kf[4];
#pragma unroll
            for (int ks = 0; ks < 4; ++ks)
                kf[ks] = __builtin_bit_cast(bf16x8, *(const ushortx8*)(
                    kc + kbase + (((ks * 2 + hi) ^ sw7) << 4)));

            f32x16 s0 = z16;
            __builtin_amdgcn_s_setprio(1);
#pragma unroll
            for (int ks = 0; ks < 4; ++ks)
                s0 = __builtin_amdgcn_mfma_f32_32x32x16_bf16(kf[ks], qf[ks], s0, 0, 0, 0);
            __builtin_amdgcn_s_setprio(0);

            // ---- fixed-M softmax: branch-free, no cross-lane ops ----
            float p[16];
#pragma unroll
            for (int r = 0; r < 16; ++r) p[r] = fexp2(s0[r] - MFIX);
            float q0 = (p[0] + p[1]) + (p[2] + p[3]);
            float q1 = (p[4] + p[5]) + (p[6] + p[7]);
            float q2 = (p[8] + p[9]) + (p[10] + p[11]);
            float q3 = (p[12] + p[13]) + (p[14] + p[15]);
            ls0 += (q0 + q1) + (q2 + q3);
            unsigned c0 = cvtpk_bf16(p[0], p[1]);
            unsigned c1 = cvtpk_bf16(p[2], p[3]);
            unsigned c2 = cvtpk_bf16(p[4], p[5]);
            unsigned c3 = cvtpk_bf16(p[6], p[7]);
            unsigned c4 = cvtpk_bf16(p[8], p[9]);
            unsigned c5 = cvtpk_bf16(p[10], p[11]);
            unsigned c6 = cvtpk_bf16(p[12], p[13]);
            unsigned c7x = cvtpk_bf16(p[14], p[15]);
            pswap(c0, c2); pswap(c1, c3); pswap(c4, c6); pswap(c5, c7x);
            bf16x8 pfa, pfb;
            { uintx4 u; u[0] = c0; u[1] = c1; u[2] = c2; u[3] = c3;
              pfa = __builtin_bit_cast(bf16x8, u); }
            { uintx4 u; u[0] = c4; u[1] = c5; u[2] = c6; u[3] = c7x;
              pfb = __builtin_bit_cast(bf16x8, u); }

            // ---- O^T += V^T P^T ----
            __builtin_amdgcn_s_setprio(1);
            {
                const int vb0 = l31 * 128;
                bf16x8 vf0 = __builtin_bit_cast(bf16x8, *(const ushortx8*)(
                    vc + vb0 + ((((c * 2 + 0) * 2 + hi) ^ sw7) << 4)));
                bf16x8 vf1 = __builtin_bit_cast(bf16x8, *(const ushortx8*)(
                    vc + vb0 + ((((c * 2 + 1) * 2 + hi) ^ sw7) << 4)));
                oa0 = __builtin_amdgcn_mfma_f32_32x32x16_bf16(vf0, pfa, oa0, 0, 0, 0);
                oa0 = __builtin_amdgcn_mfma_f32_32x32x16_bf16(vf1, pfb, oa0, 0, 0, 0);
            }
            {
                const int vb1 = (32 + l31) * 128;
                bf16x8 vf0 = __builtin_bit_cast(bf16x8, *(const ushortx8*)(
                    vc + vb1 + ((((c * 2 + 0) * 2 + hi) ^ sw7) << 4)));
                bf16x8 vf1 = __builtin_bit_cast(bf16x8, *(const ushortx8*)(
                    vc + vb1 + ((((c * 2 + 1) * 2 + hi) ^ sw7) << 4)));
                oa1 = __builtin_amdgcn_mfma_f32_32x32x16_bf16(vf0, pfa, oa1, 0, 0, 0);
                oa1 = __builtin_amdgcn_mfma_f32_32x32x16_bf16(vf1, pfb, oa1, 0, 0, 0);
            }
            __builtin_amdgcn_s_setprio(0);
        }

        __syncthreads();                 // drains prefetch glds + orders dbuf
        cur ^= 1;
    }

    // epilogue: bf16-pack unnormalized O partials, coalesced dump
    const int pidx = (qt * 8 + bh) * NSPLIT + sp;
#define STORE_OA(OA, DT)                                                      \
    {                                                                         \
        uintx4 u0, u1;                                                        \
        u0[0] = cvtpk_bf16(OA[0], OA[1]);  u0[1] = cvtpk_bf16(OA[2], OA[3]);  \
        u0[2] = cvtpk_bf16(OA[4], OA[5]);  u0[3] = cvtpk_bf16(OA[6], OA[7]);  \
        u1[0] = cvtpk_bf16(OA[8], OA[9]);  u1[1] = cvtpk_bf16(OA[10], OA[11]);\
        u1[2] = cvtpk_bf16(OA[12], OA[13]);u1[3] = cvtpk_bf16(OA[14], OA[15]);\
        uint_t* dst = opart +                                                 \
            (((size_t)pidx * 8 + wv) * 2 + (DT)) * 512 + lane * 8;            \
        *(uintx4*)dst = u0; *(uintx4*)(dst + 4) = u1;                         \
    }
    STORE_OA(oa0, 0) STORE_OA(oa1, 1)

    ls0 += __shfl_xor(ls0, 32, 64);      // combine the two key halves once
    if (hi == 0)
        lspart[(pidx * 8 + wv) * 32 + l31] = ls0;
}

// ---------------------------------------------------------------------------
// Combine NSPLIT partials (den = sum of ls; fixed-M => no exp), normalize,
// write out twice. grid (16 qt, 8 bh), 512 thr mirroring attn lanes.
__global__ __launch_bounds__(512) void combine_kernel(
    const uint_t* __restrict__ opart, const float* __restrict__ lspart,
    float* __restrict__ out)
{
    const int qt = blockIdx.x, bh = blockIdx.y;
    const int b = bh >> 1, h = bh & 1;
    const int t = threadIdx.x, lane = t & 63, wa = t >> 6;
    const int l31 = lane & 31, hi = lane >> 5;
    const int pbase = (qt * 8 + bh) * NSPLIT;
    const int dtbl[8] = {0, 2, 8, 10, 16, 18, 24, 26};

    float den = 0.f;
#pragma unroll
    for (int sp = 0; sp < NSPLIT; ++sp)
        den += lspart[((pbase + sp) * 8 + wa) * 32 + l31];
    float inv = 1.f / den;

    const int q = qt * 256 + wa * 32 + l31;
#pragma unroll
    for (int dt = 0; dt < 2; ++dt) {
        float acc[16];
#pragma unroll
        for (int i = 0; i < 16; ++i) acc[i] = 0.f;
#pragma unroll
        for (int sp = 0; sp < NSPLIT; ++sp) {
            const uint_t* src = opart +
                (((size_t)(pbase + sp) * 8 + wa) * 2 + dt) * 512 + lane * 8;
            uintx4 a = *(const uintx4*)src;
            uintx4 b2 = *(const uintx4*)(src + 4);
#pragma unroll
            for (int j = 0; j < 4; ++j) {
                acc[2 * j]     += bflo(a[j]);
                acc[2 * j + 1] += bfhi(a[j]);
                acc[8 + 2 * j] += bflo(b2[j]);
                acc[9 + 2 * j] += bfhi(b2[j]);
            }
        }
#pragma unroll
        for (int j = 0; j < 8; ++j) {
            int d = dt * 32 + 4 * hi + dtbl[j];
            float v0 = acc[2 * j] * inv;
            float v1 = acc[2 * j + 1] * inv;
            size_t o0 = ((size_t)(b * 128 + d * 2 + h)) * 4096 + q;
            out[o0] = v0;
            out[o0 + OUT_HALF] = v0;
            size_t o1 = o0 + 2 * 4096;
            out[o1] = v1;
            out[o1 + OUT_HALF] = v1;
        }
    }
}

// ---------------------------------------------------------------------------
extern "C" void kernel_launch(void* const* d_in, const int* in_sizes, int n_in,
                              void* d_out, int out_size, void* d_ws, size_t ws_size,
                              hipStream_t stream) {
    const float* x  = (const float*)d_in[0];
    const float* wq = (const float*)d_in[1];
    const float* bq = (const float*)d_in[2];
    const float* wk = (const float*)d_in[3];
    const float* bk = (const float*)d_in[4];
    const float* wv = (const float*)d_in[5];
    const float* bv = (const float*)d_in[6];
    const float* pe = (const float*)d_in[7];
    float* out = (float*)d_out;

    char* ws = (char*)d_ws;
    float*    pet   = (float*)ws;                                   // 2 MB
    ushort_t* qw    = (ushort_t*)(ws + (size_t)2  * 1024 * 1024);   // 4 MB
    ushort_t* kw    = (ushort_t*)(ws + (size_t)6  * 1024 * 1024);   // 4 MB
    ushort_t* vw    = (ushort_t*)(ws + (size_t)10 * 1024 * 1024);   // 4 MB
    uint_t*   opart = (uint_t*)(ws + (size_t)14 * 1024 * 1024);     // 16 MB (attn)
    float*    lsprt = (float*)(ws + (size_t)31 * 1024 * 1024);      // 0.5 MB (attn)
    ushort_t* wb    = (ushort_t*)(ws + (size_t)31 * 1024 * 1024);   // 96 KB (proj, dies before attn)

    hipLaunchKernelGGL(prep_kernel, dim3(1048), dim3(256), 0, stream,
                       pe, wq, wk, wv, pet, wb);
    hipLaunchKernelGGL(proj_kernel, dim3(64, 4, 3), dim3(256), 0, stream,
                       x, wb, bq, bk, bv, pet, qw, kw, vw);
    hipLaunchKernelGGL(attn_kernel, dim3(16, 8, NSPLIT), dim3(512), 0, stream,
                       qw, kw, vw, opart, lsprt);
    hipLaunchKernelGGL(combine_kernel, dim3(16, 8), dim3(512), 0, stream,
                       opart, lsprt, out);
}

// Round 19
// 69.186 us; speedup vs baseline: 1.0696x; 1.0319x over previous
//
#include <hip/hip_runtime.h>
#include <hip/hip_bf16.h>
#include <math.h>

typedef unsigned short ushort_t;
typedef unsigned int   uint_t;
typedef unsigned short ushortx8 __attribute__((ext_vector_type(8)));
typedef unsigned short ushortx4 __attribute__((ext_vector_type(4)));
typedef unsigned int   uintx4   __attribute__((ext_vector_type(4)));
typedef __bf16        bf16x8   __attribute__((ext_vector_type(8)));
typedef float         f32x4    __attribute__((ext_vector_type(4)));
typedef float         f32x16   __attribute__((ext_vector_type(16)));

#define SCALE_QL (0.29730177875068026f * 1.4426950408889634f) /* 128^-.25 * log2e */
#define OUT_HALF 2097152               /* B*C*H*W elements */
#define NSPLIT   4
#define KT_SPLIT 16                    /* 64-key tiles per split (1024 keys) */

// COMPILER-KNOWN exp2 (not inline asm!). CDNA mandates wait-states between an
// MFMA D-write and a VALU read of it; the hazard recognizer only pads KNOWN
// instructions. Inline-asm v_exp_f32 reading the MFMA accumulator directly
// (R14/15/17/18) violated the hazard -> garbage. Intrinsic is hazard-safe.
static __device__ __forceinline__ float fexp2(float x) {
#if __has_builtin(__builtin_amdgcn_exp2f)
    return __builtin_amdgcn_exp2f(x);
#else
    return exp2f(x);
#endif
}
static __device__ __forceinline__ unsigned cvtpk_bf16(float lo, float hi) {
    unsigned r;
    asm("v_cvt_pk_bf16_f32 %0, %1, %2" : "=v"(r) : "v"(lo), "v"(hi));
    return r;
}
static __device__ __forceinline__ void pswap(unsigned& a, unsigned& b) {
    asm("v_permlane32_swap_b32 %0, %1" : "+v"(a), "+v"(b));
}
static __device__ __forceinline__ ushort_t bf16u(float f) {
    __hip_bfloat16 h = __float2bfloat16(f);
    return __builtin_bit_cast(ushort_t, h);
}
static __device__ __forceinline__ float bflo(unsigned u) {
    return __builtin_bit_cast(float, u << 16);
}
static __device__ __forceinline__ float bfhi(unsigned u) {
    return __builtin_bit_cast(float, u & 0xffff0000u);
}
static __device__ __forceinline__ void glds16(const void* g, void* l) {
    __builtin_amdgcn_global_load_lds(
        (const __attribute__((address_space(1))) unsigned int*)g,
        (__attribute__((address_space(3))) unsigned int*)l, 16, 0, 0);
}

// ---------------------------------------------------------------------------
// prep: pe [n][d][h] -> pet [h][n][d] f32;  wq/wk/wv f32 -> wb bf16 with
// row-local 16B-chunk xor swizzle (chunk ^= o&15) baked in.
__global__ __launch_bounds__(256) void prep_kernel(
    const float* __restrict__ pe,
    const float* __restrict__ wq, const float* __restrict__ wk,
    const float* __restrict__ wv,
    float* __restrict__ pet, ushort_t* __restrict__ wb)
{
    const int bid = blockIdx.x, t = threadIdx.x;
    if (bid < 1024) {
        int idx = bid * 256 + t;
        float2 p2 = *(const float2*)(pe + (size_t)idx * 2);
        pet[idx]                     = p2.x;
        pet[(size_t)4096 * 64 + idx] = p2.y;
        return;
    }
    const int b2 = bid - 1024;                 // 0..23
    const int p  = b2 >> 3;
    const float* w = (p == 0) ? wq : (p == 1) ? wk : wv;
    const int cid = (b2 & 7) * 256 + t;        // 16B-chunk id 0..2047
    const int o = cid >> 4, chunk = cid & 15;
    float4 f0 = *(const float4*)(w + o * 128 + chunk * 8);
    float4 f1 = *(const float4*)(w + o * 128 + chunk * 8 + 4);
    ushortx8 u;
    u[0] = bf16u(f0.x); u[1] = bf16u(f0.y); u[2] = bf16u(f0.z); u[3] = bf16u(f0.w);
    u[4] = bf16u(f1.x); u[5] = bf16u(f1.y); u[6] = bf16u(f1.z); u[7] = bf16u(f1.w);
    *(ushortx8*)(wb + p * 16384 + o * 128 + ((chunk ^ (o & 15)) << 3)) = u;
}

// ---------------------------------------------------------------------------
// Fused transpose + MFMA projection: per block 128 outputs x 64 tokens,
// K=128, ONE projection per block (p = blockIdx.z -> 768 blocks, 3/CU).
// grid (64 ntile, 4 b, 3 p), 256 thr (4 waves, each 32 output rows).
__global__ __launch_bounds__(256, 2) void proj_kernel(
    const float* __restrict__ x, const ushort_t* __restrict__ wb,
    const float* __restrict__ bq, const float* __restrict__ bk,
    const float* __restrict__ bv, const float* __restrict__ pet,
    ushort_t* __restrict__ qw, ushort_t* __restrict__ kw,
    ushort_t* __restrict__ vw)
{
    const int ntl = blockIdx.x;        // 64-token tile
    const int b = blockIdx.y, p = blockIdx.z;
    __shared__ __align__(16) ushort_t xt[64 * 128];            // [n64][c128] swz
    __shared__ __align__(16) union {
        ushort_t xs[128][68];                                   // staging
        ushort_t wt[16384];                                     // [o128][c128] swz
    } smu;
    const int t = threadIdx.x, lane = t & 63;
    const int wv_ = __builtin_amdgcn_readfirstlane(t >> 6);
    const int l16 = lane & 15, lhi = lane >> 4;

    // phase 1: x f32 [c][n-tile] -> bf16 xs[c][n]
    {
        const int cg = t >> 4, n0 = (t & 15) * 4;
#pragma unroll
        for (int i = 0; i < 8; ++i) {
            int c = i * 16 + cg;
            float4 f = *(const float4*)(x + ((size_t)(b * 128 + c)) * 4096 + ntl * 64 + n0);
            ushortx4 u;
            u[0] = bf16u(f.x); u[1] = bf16u(f.y); u[2] = bf16u(f.z); u[3] = bf16u(f.w);
            *(ushortx4*)(&smu.xs[c][n0]) = u;
        }
    }
    __syncthreads();
    // phase 2: transpose into xt[n][c], chunk-swizzled per row
    {
        const int n = t >> 2;
#pragma unroll
        for (int j = 0; j < 4; ++j) {
            int chunk = (t & 3) * 4 + j;
            ushortx8 u;
#pragma unroll
            for (int e = 0; e < 8; ++e) u[e] = smu.xs[chunk * 8 + e][n];
            *(ushortx8*)(xt + n * 128 + ((chunk ^ (n & 15)) << 3)) = u;
        }
    }
    __syncthreads();                   // xs reads done; wt may be overwritten

    // stage W for this p
    {
        const ushort_t* wsrc = wb + p * 16384;
#pragma unroll
        for (int j = 0; j < 8; ++j) {
            int row = wv_ * 32 + j * 4;
            glds16(wsrc + row * 128 + lane * 8, smu.wt + row * 128);
        }
    }

    const float* bias = (p == 0) ? bq : (p == 1) ? bk : bv;
    f32x4 bias4[2];
    bias4[0] = *(const f32x4*)(bias + wv_ * 32 + lhi * 4);
    bias4[1] = *(const f32x4*)(bias + wv_ * 32 + 16 + lhi * 4);
    f32x4 acc[2][4];
#pragma unroll
    for (int mf = 0; mf < 2; ++mf)
#pragma unroll
        for (int nf = 0; nf < 4; ++nf) acc[mf][nf] = bias4[mf];

    __syncthreads();                   // wt staged (barrier drains glds)

    const int nbase = ntl * 64;
    const char* xbp = (const char*)xt;
    const char* wbp = (const char*)smu.wt;
#pragma unroll
    for (int ks = 0; ks < 4; ++ks) {
        bf16x8 af[2];
#pragma unroll
        for (int mf = 0; mf < 2; ++mf) {
            int row = wv_ * 32 + mf * 16 + l16;
            af[mf] = __builtin_bit_cast(bf16x8, *(const ushortx8*)(
                wbp + row * 256 + ((((ks * 4 + lhi) ^ l16) & 15) << 4)));
        }
#pragma unroll
        for (int nf = 0; nf < 4; ++nf) {
            int row = nf * 16 + l16;
            bf16x8 bfr = __builtin_bit_cast(bf16x8, *(const ushortx8*)(
                xbp + row * 256 + ((((ks * 4 + lhi) ^ l16) & 15) << 4)));
            acc[0][nf] = __builtin_amdgcn_mfma_f32_16x16x32_bf16(af[0], bfr, acc[0][nf], 0, 0, 0);
            acc[1][nf] = __builtin_amdgcn_mfma_f32_16x16x32_bf16(af[1], bfr, acc[1][nf], 0, 0, 0);
        }
    }

    if (p == 2) {                      // V -> d-major [bh][d][n]
#pragma unroll
        for (int mf = 0; mf < 2; ++mf) {
            int o = wv_ * 32 + mf * 16 + lhi * 4;
            int h = o >> 6, d = o & 63;
            ushort_t* vb = vw + (((size_t)(b * 2 + h) * 64 + d)) * 4096 + nbase + l16;
#pragma unroll
            for (int nf = 0; nf < 4; ++nf)
#pragma unroll
                for (int r = 0; r < 4; ++r)
                    vb[(size_t)r * 4096 + nf * 16] = bf16u(acc[mf][nf][r]);
        }
    } else if (p == 0) {               // Q: +pe, *scale, token-major
#pragma unroll
        for (int mf = 0; mf < 2; ++mf) {
            int o = wv_ * 32 + mf * 16 + lhi * 4;
            int h = o >> 6, d = o & 63;
#pragma unroll
            for (int nf = 0; nf < 4; ++nf) {
                int n = nbase + nf * 16 + l16;
                f32x4 pe4 = *(const f32x4*)(pet + ((size_t)h * 4096 + n) * 64 + d);
                f32x4 q4 = (acc[mf][nf] + pe4) * SCALE_QL;
                ushortx4 s;
                s[0] = bf16u(q4[0]); s[1] = bf16u(q4[1]);
                s[2] = bf16u(q4[2]); s[3] = bf16u(q4[3]);
                *(ushortx4*)(qw + ((size_t)(b * 2 + h) * 4096 + n) * 64 + d) = s;
            }
        }
    } else {                           // K: token-major
#pragma unroll
        for (int mf = 0; mf < 2; ++mf) {
            int o = wv_ * 32 + mf * 16 + lhi * 4;
            int h = o >> 6, d = o & 63;
#pragma unroll
            for (int nf = 0; nf < 4; ++nf) {
                int n = nbase + nf * 16 + l16;
                f32x4 k4 = acc[mf][nf];
                ushortx4 s;
                s[0] = bf16u(k4[0]); s[1] = bf16u(k4[1]);
                s[2] = bf16u(k4[2]); s[3] = bf16u(k4[3]);
                *(ushortx4*)(kw + ((size_t)(b * 2 + h) * 4096 + n) * 64 + d) = s;
            }
        }
    }
}

// ---------------------------------------------------------------------------
// Flash attention, 32x32 MFMA, swapped (S^T = K*Q), 32 q per wave,
// 8 waves (512 thr). Softmax p = exp2(s) with NO shift — safe only because
// fexp2 is now the compiler intrinsic (hazard-managed); scores peak ~+30 in
// log2 domain, f32/bf16 headroom 1e38, normalization cancels the scale.
// XCD remap: 16 qt-blocks sharing one (bh,sp) KV split on one XCD L2.
// K,V double-buffered LDS (32 KB), glds16 prefetch, 1 barrier/iter.
// grid (16 qtile(256q), 8 bh, NSPLIT).
__global__ __launch_bounds__(512, 4) void attn_kernel(
    const ushort_t* __restrict__ qw, const ushort_t* __restrict__ kw,
    const ushort_t* __restrict__ vw, uint_t* __restrict__ opart,
    float* __restrict__ lspart)
{
    // bijective XCD remap: raw -> swb=(raw&7)*64+(raw>>3) (512 = 8*64).
    const int raw = blockIdx.x + 16 * (blockIdx.y + 8 * blockIdx.z);
    const int swb = (raw & 7) * 64 + (raw >> 3);
    const int qt = swb & 15, bh = (swb >> 4) & 7, sp = swb >> 7;
    const int t = threadIdx.x, lane = t & 63;
    const int wv = t >> 6;                       // 0..7
    const int l31 = lane & 31, hi = lane >> 5;

    __shared__ __align__(16) ushort_t Kt[2 * 64 * 64];   // dbuf [key][d] swz
    __shared__ __align__(16) ushort_t Vt[2 * 64 * 64];   // dbuf [d][key] swz

    // Q B-frags [ks]: lane holds Q[q = qb+l31][d = ks*16+hi*8 ..+8]
    const int qb = qt * 256 + wv * 32;
    bf16x8 qf[4];
#pragma unroll
    for (int ks = 0; ks < 4; ++ks)
        qf[ks] = __builtin_bit_cast(bf16x8, *(const ushortx8*)(
            qw + ((size_t)bh * 4096 + qb + l31) * 64 + ks * 16 + hi * 8));

    const ushort_t* kgb = kw + ((size_t)bh * 4096) * 64;
    const ushort_t* vgb = vw + ((size_t)bh * 64) * 4096;

    // staging: wave covers rows [wv*8, wv*8+8); source pre-XOR-swizzled.
    const int srow = lane >> 3, c7 = lane & 7;
    const int rb = wv * 8;
    const int swz = (c7 ^ srow) << 3;
    const size_t koff = (size_t)(rb + srow) * 64 + swz;
    const size_t voff = (size_t)(rb + srow) * 4096 + swz;

    const f32x16 z16 = {0,0,0,0,0,0,0,0,0,0,0,0,0,0,0,0};
    f32x16 oa0 = z16, oa1 = z16;       // O^T[d 0..31 | 32..63][q=l31]
    float ls0 = 0.f;                   // per-lane half-sum

    const int kt0 = sp * KT_SPLIT;

#define STAGE(buf, ktb)                                                       \
    {                                                                         \
        glds16(kgb + (size_t)(ktb) * 4096 + koff,                             \
               Kt + (buf) * 4096 + (size_t)rb * 64);                          \
        glds16(vgb + (size_t)(ktb) * 64 + voff,                               \
               Vt + (buf) * 4096 + (size_t)rb * 64);                          \
    }

    STAGE(0, kt0)
    __syncthreads();

    const int sw7 = l31 & 7;
    int cur = 0;
    for (int it = 0; it < KT_SPLIT; ++it) {
        const int itn = (it + 1 < KT_SPLIT) ? it + 1 : it;
        STAGE(cur ^ 1, kt0 + itn)

        const char* kc = (const char*)(Kt + cur * 4096);
        const char* vc = (const char*)(Vt + cur * 4096);

#pragma unroll
        for (int c = 0; c < 2; ++c) {            // 32-key chain
            const int kbase = (c * 32 + l31) * 128;
            bf16x8 kf[4];
#pragma unroll
            for (int ks = 0; ks < 4; ++ks)
                kf[ks] = __builtin_bit_cast(bf16x8, *(const ushortx8*)(
                    kc + kbase + (((ks * 2 + hi) ^ sw7) << 4)));

            f32x16 s0 = z16;
            __builtin_amdgcn_s_setprio(1);
#pragma unroll
            for (int ks = 0; ks < 4; ++ks)
                s0 = __builtin_amdgcn_mfma_f32_32x32x16_bf16(kf[ks], qf[ks], s0, 0, 0, 0);
            __builtin_amdgcn_s_setprio(0);

            // ---- softmax: p = exp2(s) via intrinsic, no cross-lane ops ----
            float p[16];
#pragma unroll
            for (int r = 0; r < 16; ++r) p[r] = fexp2(s0[r]);
            float q0 = (p[0] + p[1]) + (p[2] + p[3]);
            float q1 = (p[4] + p[5]) + (p[6] + p[7]);
            float q2 = (p[8] + p[9]) + (p[10] + p[11]);
            float q3 = (p[12] + p[13]) + (p[14] + p[15]);
            ls0 += (q0 + q1) + (q2 + q3);
            unsigned c0 = cvtpk_bf16(p[0], p[1]);
            unsigned c1 = cvtpk_bf16(p[2], p[3]);
            unsigned c2 = cvtpk_bf16(p[4], p[5]);
            unsigned c3 = cvtpk_bf16(p[6], p[7]);
            unsigned c4 = cvtpk_bf16(p[8], p[9]);
            unsigned c5 = cvtpk_bf16(p[10], p[11]);
            unsigned c6 = cvtpk_bf16(p[12], p[13]);
            unsigned c7x = cvtpk_bf16(p[14], p[15]);
            pswap(c0, c2); pswap(c1, c3); pswap(c4, c6); pswap(c5, c7x);
            bf16x8 pfa, pfb;
            { uintx4 u; u[0] = c0; u[1] = c1; u[2] = c2; u[3] = c3;
              pfa = __builtin_bit_cast(bf16x8, u); }
            { uintx4 u; u[0] = c4; u[1] = c5; u[2] = c6; u[3] = c7x;
              pfb = __builtin_bit_cast(bf16x8, u); }

            // ---- O^T += V^T P^T ----
            __builtin_amdgcn_s_setprio(1);
            {
                const int vb0 = l31 * 128;
                bf16x8 vf0 = __builtin_bit_cast(bf16x8, *(const ushortx8*)(
                    vc + vb0 + ((((c * 2 + 0) * 2 + hi) ^ sw7) << 4)));
                bf16x8 vf1 = __builtin_bit_cast(bf16x8, *(const ushortx8*)(
                    vc + vb0 + ((((c * 2 + 1) * 2 + hi) ^ sw7) << 4)));
                oa0 = __builtin_amdgcn_mfma_f32_32x32x16_bf16(vf0, pfa, oa0, 0, 0, 0);
                oa0 = __builtin_amdgcn_mfma_f32_32x32x16_bf16(vf1, pfb, oa0, 0, 0, 0);
            }
            {
                const int vb1 = (32 + l31) * 128;
                bf16x8 vf0 = __builtin_bit_cast(bf16x8, *(const ushortx8*)(
                    vc + vb1 + ((((c * 2 + 0) * 2 + hi) ^ sw7) << 4)));
                bf16x8 vf1 = __builtin_bit_cast(bf16x8, *(const ushortx8*)(
                    vc + vb1 + ((((c * 2 + 1) * 2 + hi) ^ sw7) << 4)));
                oa1 = __builtin_amdgcn_mfma_f32_32x32x16_bf16(vf0, pfa, oa1, 0, 0, 0);
                oa1 = __builtin_amdgcn_mfma_f32_32x32x16_bf16(vf1, pfb, oa1, 0, 0, 0);
            }
            __builtin_amdgcn_s_setprio(0);
        }

        __syncthreads();                 // drains prefetch glds + orders dbuf
        cur ^= 1;
    }

    // epilogue: bf16-pack unnormalized O partials, coalesced dump
    const int pidx = (qt * 8 + bh) * NSPLIT + sp;
#define STORE_OA(OA, DT)                                                      \
    {                                                                         \
        uintx4 u0, u1;                                                        \
        u0[0] = cvtpk_bf16(OA[0], OA[1]);  u0[1] = cvtpk_bf16(OA[2], OA[3]);  \
        u0[2] = cvtpk_bf16(OA[4], OA[5]);  u0[3] = cvtpk_bf16(OA[6], OA[7]);  \
        u1[0] = cvtpk_bf16(OA[8], OA[9]);  u1[1] = cvtpk_bf16(OA[10], OA[11]);\
        u1[2] = cvtpk_bf16(OA[12], OA[13]);u1[3] = cvtpk_bf16(OA[14], OA[15]);\
        uint_t* dst = opart +                                                 \
            (((size_t)pidx * 8 + wv) * 2 + (DT)) * 512 + lane * 8;            \
        *(uintx4*)dst = u0; *(uintx4*)(dst + 4) = u1;                         \
    }
    STORE_OA(oa0, 0) STORE_OA(oa1, 1)

    ls0 += __shfl_xor(ls0, 32, 64);      // combine the two key halves once
    if (hi == 0)
        lspart[(pidx * 8 + wv) * 32 + l31] = ls0;
}

// ---------------------------------------------------------------------------
// Combine NSPLIT partials (den = sum of ls), normalize, write out twice.
// grid (16 qt, 8 bh), 512 thr mirroring attn lanes.
__global__ __launch_bounds__(512) void combine_kernel(
    const uint_t* __restrict__ opart, const float* __restrict__ lspart,
    float* __restrict__ out)
{
    const int qt = blockIdx.x, bh = blockIdx.y;
    const int b = bh >> 1, h = bh & 1;
    const int t = threadIdx.x, lane = t & 63, wa = t >> 6;
    const int l31 = lane & 31, hi = lane >> 5;
    const int pbase = (qt * 8 + bh) * NSPLIT;
    const int dtbl[8] = {0, 2, 8, 10, 16, 18, 24, 26};

    float den = 0.f;
#pragma unroll
    for (int sp = 0; sp < NSPLIT; ++sp)
        den += lspart[((pbase + sp) * 8 + wa) * 32 + l31];
    float inv = 1.f / den;

    const int q = qt * 256 + wa * 32 + l31;
#pragma unroll
    for (int dt = 0; dt < 2; ++dt) {
        float acc[16];
#pragma unroll
        for (int i = 0; i < 16; ++i) acc[i] = 0.f;
#pragma unroll
        for (int sp = 0; sp < NSPLIT; ++sp) {
            const uint_t* src = opart +
                (((size_t)(pbase + sp) * 8 + wa) * 2 + dt) * 512 + lane * 8;
            uintx4 a = *(const uintx4*)src;
            uintx4 b2 = *(const uintx4*)(src + 4);
#pragma unroll
            for (int j = 0; j < 4; ++j) {
                acc[2 * j]     += bflo(a[j]);
                acc[2 * j + 1] += bfhi(a[j]);
                acc[8 + 2 * j] += bflo(b2[j]);
                acc[9 + 2 * j] += bfhi(b2[j]);
            }
        }
#pragma unroll
        for (int j = 0; j < 8; ++j) {
            int d = dt * 32 + 4 * hi + dtbl[j];
            float v0 = acc[2 * j] * inv;
            float v1 = acc[2 * j + 1] * inv;
            size_t o0 = ((size_t)(b * 128 + d * 2 + h)) * 4096 + q;
            out[o0] = v0;
            out[o0 + OUT_HALF] = v0;
            size_t o1 = o0 + 2 * 4096;
            out[o1] = v1;
            out[o1 + OUT_HALF] = v1;
        }
    }
}

// ---------------------------------------------------------------------------
extern "C" void kernel_launch(void* const* d_in, const int* in_sizes, int n_in,
                              void* d_out, int out_size, void* d_ws, size_t ws_size,
                              hipStream_t stream) {
    const float* x  = (const float*)d_in[0];
    const float* wq = (const float*)d_in[1];
    const float* bq = (const float*)d_in[2];
    const float* wk = (const float*)d_in[3];
    const float* bk = (const float*)d_in[4];
    const float* wv = (const float*)d_in[5];
    const float* bv = (const float*)d_in[6];
    const float* pe = (const float*)d_in[7];
    float* out = (float*)d_out;

    char* ws = (char*)d_ws;
    float*    pet   = (float*)ws;                                   // 2 MB
    ushort_t* qw    = (ushort_t*)(ws + (size_t)2  * 1024 * 1024);   // 4 MB
    ushort_t* kw    = (ushort_t*)(ws + (size_t)6  * 1024 * 1024);   // 4 MB
    ushort_t* vw    = (ushort_t*)(ws + (size_t)10 * 1024 * 1024);   // 4 MB
    uint_t*   opart = (uint_t*)(ws + (size_t)14 * 1024 * 1024);     // 16 MB (attn)
    float*    lsprt = (float*)(ws + (size_t)31 * 1024 * 1024);      // 0.5 MB (attn)
    ushort_t* wb    = (ushort_t*)(ws + (size_t)31 * 1024 * 1024);   // 96 KB (proj, dies before attn)

    hipLaunchKernelGGL(prep_kernel, dim3(1048), dim3(256), 0, stream,
                       pe, wq, wk, wv, pet, wb);
    hipLaunchKernelGGL(proj_kernel, dim3(64, 4, 3), dim3(256), 0, stream,
                       x, wb, bq, bk, bv, pet, qw, kw, vw);
    hipLaunchKernelGGL(attn_kernel, dim3(16, 8, NSPLIT), dim3(512), 0, stream,
                       qw, kw, vw, opart, lsprt);
    hipLaunchKernelGGL(combine_kernel, dim3(16, 8), dim3(512), 0, stream,
                       opart, lsprt, out);
}

// Round 20
// 67.822 us; speedup vs baseline: 1.0912x; 1.0201x over previous
//
#include <hip/hip_runtime.h>
#include <hip/hip_bf16.h>
#include <math.h>

typedef unsigned short ushort_t;
typedef unsigned int   uint_t;
typedef unsigned short ushortx8 __attribute__((ext_vector_type(8)));
typedef unsigned short ushortx4 __attribute__((ext_vector_type(4)));
typedef unsigned int   uintx4   __attribute__((ext_vector_type(4)));
typedef __bf16        bf16x8   __attribute__((ext_vector_type(8)));
typedef float         f32x4    __attribute__((ext_vector_type(4)));
typedef float         f32x16   __attribute__((ext_vector_type(16)));

#define SCALE_QL (0.29730177875068026f * 1.4426950408889634f) /* 128^-.25 * log2e */
#define OUT_HALF 2097152               /* B*C*H*W elements */
#define NSPLIT   4
#define KT_SPLIT 16                    /* 64-key tiles per split (1024 keys) */

// COMPILER-KNOWN exp2 (not inline asm!). CDNA mandates wait-states between an
// MFMA D-write and a VALU read of it; the hazard recognizer only pads KNOWN
// instructions. Inline-asm v_exp_f32 reading the MFMA accumulator directly
// (R14/15/17/18) violated the hazard -> garbage. Intrinsic is hazard-safe.
static __device__ __forceinline__ float fexp2(float x) {
#if __has_builtin(__builtin_amdgcn_exp2f)
    return __builtin_amdgcn_exp2f(x);
#else
    return exp2f(x);
#endif
}
static __device__ __forceinline__ unsigned cvtpk_bf16(float lo, float hi) {
    unsigned r;
    asm("v_cvt_pk_bf16_f32 %0, %1, %2" : "=v"(r) : "v"(lo), "v"(hi));
    return r;
}
static __device__ __forceinline__ void pswap(unsigned& a, unsigned& b) {
    asm("v_permlane32_swap_b32 %0, %1" : "+v"(a), "+v"(b));
}
static __device__ __forceinline__ ushort_t bf16u(float f) {
    __hip_bfloat16 h = __float2bfloat16(f);
    return __builtin_bit_cast(ushort_t, h);
}
static __device__ __forceinline__ float bflo(unsigned u) {
    return __builtin_bit_cast(float, u << 16);
}
static __device__ __forceinline__ float bfhi(unsigned u) {
    return __builtin_bit_cast(float, u & 0xffff0000u);
}
static __device__ __forceinline__ void glds16(const void* g, void* l) {
    __builtin_amdgcn_global_load_lds(
        (const __attribute__((address_space(1))) unsigned int*)g,
        (__attribute__((address_space(3))) unsigned int*)l, 16, 0, 0);
}

// ---------------------------------------------------------------------------
// prep: pe [n][d][h] -> pet [h][n][d] f32;  wq/wk/wv f32 -> wb bf16 with
// row-local 16B-chunk xor swizzle (chunk ^= o&15) baked in.
__global__ __launch_bounds__(256) void prep_kernel(
    const float* __restrict__ pe,
    const float* __restrict__ wq, const float* __restrict__ wk,
    const float* __restrict__ wv,
    float* __restrict__ pet, ushort_t* __restrict__ wb)
{
    const int bid = blockIdx.x, t = threadIdx.x;
    if (bid < 1024) {
        int idx = bid * 256 + t;
        float2 p2 = *(const float2*)(pe + (size_t)idx * 2);
        pet[idx]                     = p2.x;
        pet[(size_t)4096 * 64 + idx] = p2.y;
        return;
    }
    const int b2 = bid - 1024;                 // 0..23
    const int p  = b2 >> 3;
    const float* w = (p == 0) ? wq : (p == 1) ? wk : wv;
    const int cid = (b2 & 7) * 256 + t;        // 16B-chunk id 0..2047
    const int o = cid >> 4, chunk = cid & 15;
    float4 f0 = *(const float4*)(w + o * 128 + chunk * 8);
    float4 f1 = *(const float4*)(w + o * 128 + chunk * 8 + 4);
    ushortx8 u;
    u[0] = bf16u(f0.x); u[1] = bf16u(f0.y); u[2] = bf16u(f0.z); u[3] = bf16u(f0.w);
    u[4] = bf16u(f1.x); u[5] = bf16u(f1.y); u[6] = bf16u(f1.z); u[7] = bf16u(f1.w);
    *(ushortx8*)(wb + p * 16384 + o * 128 + ((chunk ^ (o & 15)) << 3)) = u;
}

// ---------------------------------------------------------------------------
// Fused transpose + MFMA projection: per block 128 outputs x 64 tokens,
// K=128, ONE projection per block (p = blockIdx.z -> 768 blocks, 3/CU).
// grid (64 ntile, 4 b, 3 p), 256 thr (4 waves, each 32 output rows).
__global__ __launch_bounds__(256, 2) void proj_kernel(
    const float* __restrict__ x, const ushort_t* __restrict__ wb,
    const float* __restrict__ bq, const float* __restrict__ bk,
    const float* __restrict__ bv, const float* __restrict__ pet,
    ushort_t* __restrict__ qw, ushort_t* __restrict__ kw,
    ushort_t* __restrict__ vw)
{
    const int ntl = blockIdx.x;        // 64-token tile
    const int b = blockIdx.y, p = blockIdx.z;
    __shared__ __align__(16) ushort_t xt[64 * 128];            // [n64][c128] swz
    __shared__ __align__(16) union {
        ushort_t xs[128][68];                                   // staging
        ushort_t wt[16384];                                     // [o128][c128] swz
    } smu;
    const int t = threadIdx.x, lane = t & 63;
    const int wv_ = __builtin_amdgcn_readfirstlane(t >> 6);
    const int l16 = lane & 15, lhi = lane >> 4;

    // phase 1: x f32 [c][n-tile] -> bf16 xs[c][n]
    {
        const int cg = t >> 4, n0 = (t & 15) * 4;
#pragma unroll
        for (int i = 0; i < 8; ++i) {
            int c = i * 16 + cg;
            float4 f = *(const float4*)(x + ((size_t)(b * 128 + c)) * 4096 + ntl * 64 + n0);
            ushortx4 u;
            u[0] = bf16u(f.x); u[1] = bf16u(f.y); u[2] = bf16u(f.z); u[3] = bf16u(f.w);
            *(ushortx4*)(&smu.xs[c][n0]) = u;
        }
    }
    __syncthreads();
    // phase 2: transpose into xt[n][c], chunk-swizzled per row
    {
        const int n = t >> 2;
#pragma unroll
        for (int j = 0; j < 4; ++j) {
            int chunk = (t & 3) * 4 + j;
            ushortx8 u;
#pragma unroll
            for (int e = 0; e < 8; ++e) u[e] = smu.xs[chunk * 8 + e][n];
            *(ushortx8*)(xt + n * 128 + ((chunk ^ (n & 15)) << 3)) = u;
        }
    }
    __syncthreads();                   // xs reads done; wt may be overwritten

    // stage W for this p
    {
        const ushort_t* wsrc = wb + p * 16384;
#pragma unroll
        for (int j = 0; j < 8; ++j) {
            int row = wv_ * 32 + j * 4;
            glds16(wsrc + row * 128 + lane * 8, smu.wt + row * 128);
        }
    }

    const float* bias = (p == 0) ? bq : (p == 1) ? bk : bv;
    f32x4 bias4[2];
    bias4[0] = *(const f32x4*)(bias + wv_ * 32 + lhi * 4);
    bias4[1] = *(const f32x4*)(bias + wv_ * 32 + 16 + lhi * 4);
    f32x4 acc[2][4];
#pragma unroll
    for (int mf = 0; mf < 2; ++mf)
#pragma unroll
        for (int nf = 0; nf < 4; ++nf) acc[mf][nf] = bias4[mf];

    __syncthreads();                   // wt staged (barrier drains glds)

    const int nbase = ntl * 64;
    const char* xbp = (const char*)xt;
    const char* wbp = (const char*)smu.wt;
#pragma unroll
    for (int ks = 0; ks < 4; ++ks) {
        bf16x8 af[2];
#pragma unroll
        for (int mf = 0; mf < 2; ++mf) {
            int row = wv_ * 32 + mf * 16 + l16;
            af[mf] = __builtin_bit_cast(bf16x8, *(const ushortx8*)(
                wbp + row * 256 + ((((ks * 4 + lhi) ^ l16) & 15) << 4)));
        }
#pragma unroll
        for (int nf = 0; nf < 4; ++nf) {
            int row = nf * 16 + l16;
            bf16x8 bfr = __builtin_bit_cast(bf16x8, *(const ushortx8*)(
                xbp + row * 256 + ((((ks * 4 + lhi) ^ l16) & 15) << 4)));
            acc[0][nf] = __builtin_amdgcn_mfma_f32_16x16x32_bf16(af[0], bfr, acc[0][nf], 0, 0, 0);
            acc[1][nf] = __builtin_amdgcn_mfma_f32_16x16x32_bf16(af[1], bfr, acc[1][nf], 0, 0, 0);
        }
    }

    if (p == 2) {                      // V -> d-major [bh][d][n]
#pragma unroll
        for (int mf = 0; mf < 2; ++mf) {
            int o = wv_ * 32 + mf * 16 + lhi * 4;
            int h = o >> 6, d = o & 63;
            ushort_t* vb = vw + (((size_t)(b * 2 + h) * 64 + d)) * 4096 + nbase + l16;
#pragma unroll
            for (int nf = 0; nf < 4; ++nf)
#pragma unroll
                for (int r = 0; r < 4; ++r)
                    vb[(size_t)r * 4096 + nf * 16] = bf16u(acc[mf][nf][r]);
        }
    } else if (p == 0) {               // Q: +pe, *scale, token-major
#pragma unroll
        for (int mf = 0; mf < 2; ++mf) {
            int o = wv_ * 32 + mf * 16 + lhi * 4;
            int h = o >> 6, d = o & 63;
#pragma unroll
            for (int nf = 0; nf < 4; ++nf) {
                int n = nbase + nf * 16 + l16;
                f32x4 pe4 = *(const f32x4*)(pet + ((size_t)h * 4096 + n) * 64 + d);
                f32x4 q4 = (acc[mf][nf] + pe4) * SCALE_QL;
                ushortx4 s;
                s[0] = bf16u(q4[0]); s[1] = bf16u(q4[1]);
                s[2] = bf16u(q4[2]); s[3] = bf16u(q4[3]);
                *(ushortx4*)(qw + ((size_t)(b * 2 + h) * 4096 + n) * 64 + d) = s;
            }
        }
    } else {                           // K: token-major
#pragma unroll
        for (int mf = 0; mf < 2; ++mf) {
            int o = wv_ * 32 + mf * 16 + lhi * 4;
            int h = o >> 6, d = o & 63;
#pragma unroll
            for (int nf = 0; nf < 4; ++nf) {
                int n = nbase + nf * 16 + l16;
                f32x4 k4 = acc[mf][nf];
                ushortx4 s;
                s[0] = bf16u(k4[0]); s[1] = bf16u(k4[1]);
                s[2] = bf16u(k4[2]); s[3] = bf16u(k4[3]);
                *(ushortx4*)(kw + ((size_t)(b * 2 + h) * 4096 + n) * 64 + d) = s;
            }
        }
    }
}

// ---------------------------------------------------------------------------
// Flash attention, 32x32 MFMA, swapped (S^T = K*Q), 32 q per wave,
// 8 waves (512 thr). Softmax p = exp2(s) via compiler intrinsic (hazard-safe
// MFMA->VALU; inline-asm exp2 on the accumulator miscompiled in R14-R18).
// PIPELINED TILE (retry of R17, now hazard-safe): both 32-key QK halves
// (sA,sB) issued back-to-back -> 8-deep independent MFMA stream; SM(A) VALU
// overlaps the MFMA tail; sB's wait is fully covered by SM+PV(A).
// XCD remap: 16 qt-blocks sharing one (bh,sp) KV split on one XCD L2.
// K,V double-buffered LDS (32 KB), glds16 prefetch, 1 barrier/iter.
// grid (16 qtile(256q), 8 bh, NSPLIT).
__global__ __launch_bounds__(512, 4) void attn_kernel(
    const ushort_t* __restrict__ qw, const ushort_t* __restrict__ kw,
    const ushort_t* __restrict__ vw, uint_t* __restrict__ opart,
    float* __restrict__ lspart)
{
    // bijective XCD remap: raw -> swb=(raw&7)*64+(raw>>3) (512 = 8*64).
    const int raw = blockIdx.x + 16 * (blockIdx.y + 8 * blockIdx.z);
    const int swb = (raw & 7) * 64 + (raw >> 3);
    const int qt = swb & 15, bh = (swb >> 4) & 7, sp = swb >> 7;
    const int t = threadIdx.x, lane = t & 63;
    const int wv = t >> 6;                       // 0..7
    const int l31 = lane & 31, hi = lane >> 5;

    __shared__ __align__(16) ushort_t Kt[2 * 64 * 64];   // dbuf [key][d] swz
    __shared__ __align__(16) ushort_t Vt[2 * 64 * 64];   // dbuf [d][key] swz

    // Q B-frags [ks]: lane holds Q[q = qb+l31][d = ks*16+hi*8 ..+8]
    const int qb = qt * 256 + wv * 32;
    bf16x8 qf[4];
#pragma unroll
    for (int ks = 0; ks < 4; ++ks)
        qf[ks] = __builtin_bit_cast(bf16x8, *(const ushortx8*)(
            qw + ((size_t)bh * 4096 + qb + l31) * 64 + ks * 16 + hi * 8));

    const ushort_t* kgb = kw + ((size_t)bh * 4096) * 64;
    const ushort_t* vgb = vw + ((size_t)bh * 64) * 4096;

    // staging: wave covers rows [wv*8, wv*8+8); source pre-XOR-swizzled.
    const int srow = lane >> 3, c7 = lane & 7;
    const int rb = wv * 8;
    const int swz = (c7 ^ srow) << 3;
    const size_t koff = (size_t)(rb + srow) * 64 + swz;
    const size_t voff = (size_t)(rb + srow) * 4096 + swz;

    const f32x16 z16 = {0,0,0,0,0,0,0,0,0,0,0,0,0,0,0,0};
    f32x16 oa0 = z16, oa1 = z16;       // O^T[d 0..31 | 32..63][q=l31]
    float ls0 = 0.f;                   // per-lane half-sum

    const int kt0 = sp * KT_SPLIT;

#define STAGE(buf, ktb)                                                       \
    {                                                                         \
        glds16(kgb + (size_t)(ktb) * 4096 + koff,                             \
               Kt + (buf) * 4096 + (size_t)rb * 64);                          \
        glds16(vgb + (size_t)(ktb) * 64 + voff,                               \
               Vt + (buf) * 4096 + (size_t)rb * 64);                          \
    }

    STAGE(0, kt0)
    __syncthreads();

    const int sw7 = l31 & 7;
    int cur = 0;
    for (int it = 0; it < KT_SPLIT; ++it) {
        const int itn = (it + 1 < KT_SPLIT) ? it + 1 : it;
        STAGE(cur ^ 1, kt0 + itn)

        const char* kc = (const char*)(Kt + cur * 4096);
        const char* vc = (const char*)(Vt + cur * 4096);

        // ---- QK for BOTH 32-key halves up front (8-deep MFMA stream) ----
        f32x16 sA = z16, sB = z16;
        {
            bf16x8 kfA[4], kfB[4];
            const int kbA = (0 * 32 + l31) * 128;
            const int kbB = (1 * 32 + l31) * 128;
#pragma unroll
            for (int ks = 0; ks < 4; ++ks) {
                kfA[ks] = __builtin_bit_cast(bf16x8, *(const ushortx8*)(
                    kc + kbA + (((ks * 2 + hi) ^ sw7) << 4)));
                kfB[ks] = __builtin_bit_cast(bf16x8, *(const ushortx8*)(
                    kc + kbB + (((ks * 2 + hi) ^ sw7) << 4)));
            }
            __builtin_amdgcn_s_setprio(1);
#pragma unroll
            for (int ks = 0; ks < 4; ++ks)
                sA = __builtin_amdgcn_mfma_f32_32x32x16_bf16(kfA[ks], qf[ks], sA, 0, 0, 0);
#pragma unroll
            for (int ks = 0; ks < 4; ++ks)
                sB = __builtin_amdgcn_mfma_f32_32x32x16_bf16(kfB[ks], qf[ks], sB, 0, 0, 0);
            __builtin_amdgcn_s_setprio(0);
        }

        // ---- softmax + PV per half; SM(B) overlaps PV(A) on sep. pipes ----
#define SMPV(SV, CC)                                                          \
        {                                                                     \
            float p[16];                                                      \
            _Pragma("unroll")                                                 \
            for (int r = 0; r < 16; ++r) p[r] = fexp2(SV[r]);                 \
            float q0 = (p[0] + p[1]) + (p[2] + p[3]);                         \
            float q1 = (p[4] + p[5]) + (p[6] + p[7]);                         \
            float q2 = (p[8] + p[9]) + (p[10] + p[11]);                       \
            float q3 = (p[12] + p[13]) + (p[14] + p[15]);                     \
            ls0 += (q0 + q1) + (q2 + q3);                                     \
            unsigned c0 = cvtpk_bf16(p[0], p[1]);                             \
            unsigned c1 = cvtpk_bf16(p[2], p[3]);                             \
            unsigned c2 = cvtpk_bf16(p[4], p[5]);                             \
            unsigned c3 = cvtpk_bf16(p[6], p[7]);                             \
            unsigned c4 = cvtpk_bf16(p[8], p[9]);                             \
            unsigned c5 = cvtpk_bf16(p[10], p[11]);                           \
            unsigned c6 = cvtpk_bf16(p[12], p[13]);                           \
            unsigned c7x = cvtpk_bf16(p[14], p[15]);                          \
            pswap(c0, c2); pswap(c1, c3); pswap(c4, c6); pswap(c5, c7x);      \
            bf16x8 pfa, pfb;                                                  \
            { uintx4 u; u[0] = c0; u[1] = c1; u[2] = c2; u[3] = c3;           \
              pfa = __builtin_bit_cast(bf16x8, u); }                          \
            { uintx4 u; u[0] = c4; u[1] = c5; u[2] = c6; u[3] = c7x;          \
              pfb = __builtin_bit_cast(bf16x8, u); }                          \
            __builtin_amdgcn_s_setprio(1);                                    \
            {                                                                 \
                const int vb0 = l31 * 128;                                    \
                bf16x8 vf0 = __builtin_bit_cast(bf16x8, *(const ushortx8*)(   \
                    vc + vb0 + ((((CC * 2 + 0) * 2 + hi) ^ sw7) << 4)));      \
                bf16x8 vf1 = __builtin_bit_cast(bf16x8, *(const ushortx8*)(   \
                    vc + vb0 + ((((CC * 2 + 1) * 2 + hi) ^ sw7) << 4)));      \
                oa0 = __builtin_amdgcn_mfma_f32_32x32x16_bf16(vf0, pfa, oa0, 0, 0, 0); \
                oa0 = __builtin_amdgcn_mfma_f32_32x32x16_bf16(vf1, pfb, oa0, 0, 0, 0); \
            }                                                                 \
            {                                                                 \
                const int vb1 = (32 + l31) * 128;                             \
                bf16x8 vf0 = __builtin_bit_cast(bf16x8, *(const ushortx8*)(   \
                    vc + vb1 + ((((CC * 2 + 0) * 2 + hi) ^ sw7) << 4)));      \
                bf16x8 vf1 = __builtin_bit_cast(bf16x8, *(const ushortx8*)(   \
                    vc + vb1 + ((((CC * 2 + 1) * 2 + hi) ^ sw7) << 4)));      \
                oa1 = __builtin_amdgcn_mfma_f32_32x32x16_bf16(vf0, pfa, oa1, 0, 0, 0); \
                oa1 = __builtin_amdgcn_mfma_f32_32x32x16_bf16(vf1, pfb, oa1, 0, 0, 0); \
            }                                                                 \
            __builtin_amdgcn_s_setprio(0);                                    \
        }
        SMPV(sA, 0)
        SMPV(sB, 1)

        __syncthreads();                 // drains prefetch glds + orders dbuf
        cur ^= 1;
    }

    // epilogue: bf16-pack unnormalized O partials, coalesced dump
    const int pidx = (qt * 8 + bh) * NSPLIT + sp;
#define STORE_OA(OA, DT)                                                      \
    {                                                                         \
        uintx4 u0, u1;                                                        \
        u0[0] = cvtpk_bf16(OA[0], OA[1]);  u0[1] = cvtpk_bf16(OA[2], OA[3]);  \
        u0[2] = cvtpk_bf16(OA[4], OA[5]);  u0[3] = cvtpk_bf16(OA[6], OA[7]);  \
        u1[0] = cvtpk_bf16(OA[8], OA[9]);  u1[1] = cvtpk_bf16(OA[10], OA[11]);\
        u1[2] = cvtpk_bf16(OA[12], OA[13]);u1[3] = cvtpk_bf16(OA[14], OA[15]);\
        uint_t* dst = opart +                                                 \
            (((size_t)pidx * 8 + wv) * 2 + (DT)) * 512 + lane * 8;            \
        *(uintx4*)dst = u0; *(uintx4*)(dst + 4) = u1;                         \
    }
    STORE_OA(oa0, 0) STORE_OA(oa1, 1)

    ls0 += __shfl_xor(ls0, 32, 64);      // combine the two key halves once
    if (hi == 0)
        lspart[(pidx * 8 + wv) * 32 + l31] = ls0;
}

// ---------------------------------------------------------------------------
// Combine NSPLIT partials (den = sum of ls), normalize, write out twice.
// grid (16 qt, 8 bh), 512 thr mirroring attn lanes.
__global__ __launch_bounds__(512) void combine_kernel(
    const uint_t* __restrict__ opart, const float* __restrict__ lspart,
    float* __restrict__ out)
{
    const int qt = blockIdx.x, bh = blockIdx.y;
    const int b = bh >> 1, h = bh & 1;
    const int t = threadIdx.x, lane = t & 63, wa = t >> 6;
    const int l31 = lane & 31, hi = lane >> 5;
    const int pbase = (qt * 8 + bh) * NSPLIT;
    const int dtbl[8] = {0, 2, 8, 10, 16, 18, 24, 26};

    float den = 0.f;
#pragma unroll
    for (int sp = 0; sp < NSPLIT; ++sp)
        den += lspart[((pbase + sp) * 8 + wa) * 32 + l31];
    float inv = 1.f / den;

    const int q = qt * 256 + wa * 32 + l31;
#pragma unroll
    for (int dt = 0; dt < 2; ++dt) {
        float acc[16];
#pragma unroll
        for (int i = 0; i < 16; ++i) acc[i] = 0.f;
#pragma unroll
        for (int sp = 0; sp < NSPLIT; ++sp) {
            const uint_t* src = opart +
                (((size_t)(pbase + sp) * 8 + wa) * 2 + dt) * 512 + lane * 8;
            uintx4 a = *(const uintx4*)src;
            uintx4 b2 = *(const uintx4*)(src + 4);
#pragma unroll
            for (int j = 0; j < 4; ++j) {
                acc[2 * j]     += bflo(a[j]);
                acc[2 * j + 1] += bfhi(a[j]);
                acc[8 + 2 * j] += bflo(b2[j]);
                acc[9 + 2 * j] += bfhi(b2[j]);
            }
        }
#pragma unroll
        for (int j = 0; j < 8; ++j) {
            int d = dt * 32 + 4 * hi + dtbl[j];
            float v0 = acc[2 * j] * inv;
            float v1 = acc[2 * j + 1] * inv;
            size_t o0 = ((size_t)(b * 128 + d * 2 + h)) * 4096 + q;
            out[o0] = v0;
            out[o0 + OUT_HALF] = v0;
            size_t o1 = o0 + 2 * 4096;
            out[o1] = v1;
            out[o1 + OUT_HALF] = v1;
        }
    }
}

// ---------------------------------------------------------------------------
extern "C" void kernel_launch(void* const* d_in, const int* in_sizes, int n_in,
                              void* d_out, int out_size, void* d_ws, size_t ws_size,
                              hipStream_t stream) {
    const float* x  = (const float*)d_in[0];
    const float* wq = (const float*)d_in[1];
    const float* bq = (const float*)d_in[2];
    const float* wk = (const float*)d_in[3];
    const float* bk = (const float*)d_in[4];
    const float* wv = (const float*)d_in[5];
    const float* bv = (const float*)d_in[6];
    const float* pe = (const float*)d_in[7];
    float* out = (float*)d_out;

    char* ws = (char*)d_ws;
    float*    pet   = (float*)ws;                                   // 2 MB
    ushort_t* qw    = (ushort_t*)(ws + (size_t)2  * 1024 * 1024);   // 4 MB
    ushort_t* kw    = (ushort_t*)(ws + (size_t)6  * 1024 * 1024);   // 4 MB
    ushort_t* vw    = (ushort_t*)(ws + (size_t)10 * 1024 * 1024);   // 4 MB
    uint_t*   opart = (uint_t*)(ws + (size_t)14 * 1024 * 1024);     // 16 MB (attn)
    float*    lsprt = (float*)(ws + (size_t)31 * 1024 * 1024);      // 0.5 MB (attn)
    ushort_t* wb    = (ushort_t*)(ws + (size_t)31 * 1024 * 1024);   // 96 KB (proj, dies before attn)

    hipLaunchKernelGGL(prep_kernel, dim3(1048), dim3(256), 0, stream,
                       pe, wq, wk, wv, pet, wb);
    hipLaunchKernelGGL(proj_kernel, dim3(64, 4, 3), dim3(256), 0, stream,
                       x, wb, bq, bk, bv, pet, qw, kw, vw);
    hipLaunchKernelGGL(attn_kernel, dim3(16, 8, NSPLIT), dim3(512), 0, stream,
                       qw, kw, vw, opart, lsprt);
    hipLaunchKernelGGL(combine_kernel, dim3(16, 8), dim3(512), 0, stream,
                       opart, lsprt, out);
}